// Round 11
// baseline (496.555 us; speedup 1.0000x reference)
//
#include <hip/hip_runtime.h>
#include <hip/hip_fp16.h>
#include <cstddef>
#include <cstdint>

#define NN 50000
#define DEG 8
#define EE (NN*DEG)
#define RT_CNT 3125   // NN/16 row-tiles
#define KSTEPS 36     // K=1152 / 32:  [xt(4) | rel*16+tw*4+{Bm,mn,mx,std}]
#define W8L 18432     // Wcp layer stride in short8 units (KSTEPS*32*128/8)
#define MPAD 136      // f16 tile row pad (halves)
#define TPB 4         // tiles per k_agg_gemm block (pipelined)

typedef __attribute__((ext_vector_type(8))) short short8;
typedef __attribute__((ext_vector_type(4))) float f32x4;

union Pack8 { __half h[8]; __half2 h2[4]; uint4 u; };
union Pack4 { __half h[4]; uint2 u; };

// ---------------------------------------------------------------------------
// K0: build neighbor lists (constant degree 8) via atomic counters
// ---------------------------------------------------------------------------
__global__ void k_build_nbr(const int* __restrict__ ef, int* __restrict__ cnt,
                            int* __restrict__ fwd_nbr, int* __restrict__ rev_nbr) {
    int e = blockIdx.x * blockDim.x + threadIdx.x;
    if (e >= EE) return;
    int s = ef[e], d = ef[EE + e];
    int p = atomicAdd(&cnt[d], 1);
    fwd_nbr[d * DEG + p] = s;
    int q = atomicAdd(&cnt[NN + s], 1);
    rev_nbr[s * DEG + q] = d;
}

// ---------------------------------------------------------------------------
// K0w: combined-weight prep, one block per m4=(l,r,tw). Pfold folded in LDS;
// Q = P_xt + Wt@Psum3; T3 = post_b + pre_b@Psum3; stat rows -> packed f16
// MFMA-B layout; xt partial -> fp32 atomic Qw; bias -> atomic bc.
// ---------------------------------------------------------------------------
__global__ __launch_bounds__(256) void k_wprep(
    const float* __restrict__ post_W, const float* __restrict__ pre_W,
    const float* __restrict__ pre_b, const float* __restrict__ post_b,
    const float* __restrict__ lin_W, const float* __restrict__ lin_b,
    __half* __restrict__ Wcp, float* __restrict__ Qw, float* __restrict__ bc) {
    __shared__ float Pf[160 * 33];
    __shared__ float Wl[32 * 128];
    __shared__ float Wt[32 * 32];
    __shared__ float Ps[32 * 32];
    __shared__ float Q[32 * 32];
    __shared__ float T3s[32];
    int tid = threadIdx.x;
    int m4 = blockIdx.x;
    int l = m4 >> 3, r = (m4 >> 2) & 1, tw = m4 & 3;
    const float* PW = post_W + (size_t)m4 * 416 * 32;
    for (int i = tid; i < 160 * 32; i += 256) {
        int row = i >> 5, g = i & 31;
        float v;
        if (row < 32) v = PW[row * 32 + g];
        else {
            int rr = row - 32;
            v = PW[(32 + rr) * 32 + g] + PW[(160 + rr) * 32 + g] + PW[(288 + rr) * 32 + g];
        }
        Pf[row * 33 + g] = v;
    }
    for (int i = tid; i < 1024; i += 256) Wt[i] = pre_W[(size_t)m4 * 2048 + i];
    for (int i = tid; i < 4096; i += 256)
        Wl[i] = lin_W[(size_t)(l * 2 + r) * 16384 + tw * 32 * 128 + i];
    __syncthreads();
    for (int i = tid; i < 1024; i += 256) {
        int g = i >> 5, j = i & 31;
        Ps[i] = Pf[(32 + g) * 33 + j] + Pf[(64 + g) * 33 + j] + Pf[(96 + g) * 33 + j];
    }
    __syncthreads();
    for (int i = tid; i < 1024; i += 256) {
        int f = i >> 5, j = i & 31;
        float acc = Pf[f * 33 + j];
#pragma unroll
        for (int g = 0; g < 32; g++) acc += Wt[f * 32 + g] * Ps[g * 32 + j];
        Q[i] = acc;
    }
    if (tid < 32) {
        int j = tid;
        float v = post_b[m4 * 32 + j];
#pragma unroll
        for (int g = 0; g < 32; g++) v += pre_b[m4 * 32 + g] * Ps[g * 32 + j];
        T3s[j] = v;
    }
    __syncthreads();
    for (int u = tid; u < 2048; u += 256) {
        int lane = u & 63, t = (u >> 6) & 7, s = u >> 9;
        int quad = lane >> 4, nl = lane & 15;
        int n = t * 16 + nl;
        Pack8 pk;
#pragma unroll
        for (int e = 0; e < 8; e++) {
            int f = quad * 8 + e;
            const float* Pr = &Pf[((s + 1) * 32 + f) * 33];
            float acc = 0.f;
#pragma unroll
            for (int j = 0; j < 32; j++) acc += Pr[j] * Wl[j * 128 + n];
            pk.h[e] = __float2half(acc);
        }
        int ks = 4 + r * 16 + tw * 4 + s;
        *(uint4*)&Wcp[((size_t)l * W8L + (t * KSTEPS + ks) * 64 + lane) * 8] = pk.u;
    }
    for (int i = tid; i < 4096; i += 256) {
        int f = i >> 7, n = i & 127;
        float acc = 0.f;
#pragma unroll
        for (int j = 0; j < 32; j++) acc += Q[f * 32 + j] * Wl[j * 128 + n];
        atomicAdd(&Qw[(size_t)l * 16384 + (tw * 32 + f) * 128 + n], acc);
    }
    if (tid < 128) {
        float v = 0.f;
#pragma unroll
        for (int j = 0; j < 32; j++) v += T3s[j] * Wl[j * 128 + tid];
        atomicAdd(&bc[l * 128 + tid], v);
        if ((m4 & 7) == 0)
            atomicAdd(&bc[l * 128 + tid],
                      lin_b[(2 * l) * 128 + tid] + lin_b[(2 * l + 1) * 128 + tid]);
    }
}

// ---------------------------------------------------------------------------
// K0x: pack xt rows (Qw fp32) into Wcp f16 B-frag layout (ks = tw in [0,4))
// ---------------------------------------------------------------------------
__global__ void k_pack_xt(const float* __restrict__ Qw, __half* __restrict__ Wcp) {
    int gid = blockIdx.x * blockDim.x + threadIdx.x;
    if (gid >= 2 * 4 * 8 * 64) return;
    int lane = gid & 63, t = (gid >> 6) & 7, ks = (gid >> 9) & 3, l = gid >> 11;
    int quad = lane >> 4;
    int n = t * 16 + (lane & 15);
    Pack8 pk;
#pragma unroll
    for (int e = 0; e < 8; e++)
        pk.h[e] = __float2half(Qw[(size_t)l * 16384 + (ks * 32 + quad * 8 + e) * 128 + n]);
    *(uint4*)&Wcp[((size_t)l * W8L + (t * KSTEPS + ks) * 64 + lane) * 8] = pk.u;
}

// ---------------------------------------------------------------------------
// K0y: generic fp32 [K][N] -> f16 MFMA-B-frag pack
// ---------------------------------------------------------------------------
__global__ void k_pack_b(const float* __restrict__ W, int K, int N,
                         __half* __restrict__ dst) {
    int gid = blockIdx.x * blockDim.x + threadIdx.x;
    int total = (K >> 5) * (N >> 4) * 64;
    if (gid >= total) return;
    int lane = gid & 63;
    int ks = (gid >> 6) % (K >> 5);
    int t = (gid >> 6) / (K >> 5);
    int quad = lane >> 4, nl = lane & 15;
    int n = t * 16 + nl;
    Pack8 pk;
#pragma unroll
    for (int e = 0; e < 8; e++)
        pk.h[e] = __float2half(W[(size_t)(ks * 32 + quad * 8 + e) * N + n]);
    *(uint4*)&dst[(size_t)gid * 8] = pk.u;
}

// ---------------------------------------------------------------------------
// K1: input layer via MFMA: h = relu(x @ W_in + b_in), f16 output.
// ---------------------------------------------------------------------------
__global__ __launch_bounds__(256) void k_in_mfma(
    const float* __restrict__ X, const __half* __restrict__ Wp,
    const float* __restrict__ b, __half* __restrict__ H) {
    __shared__ __half Sh[4][16 * MPAD];
    int tid = threadIdx.x, wave = tid >> 6, lane = tid & 63;
    int rt = blockIdx.x * 4 + wave;
    if (rt >= RT_CNT) rt = RT_CNT - 1;  // redundant recompute, benign
    __half* T = Sh[wave];
    const float4* X4 = (const float4*)X + (size_t)rt * 16 * 32;
#pragma unroll
    for (int i = 0; i < 8; i++) {
        int idx = i * 64 + lane;
        int row = idx >> 5, col4 = idx & 31;
        float4 v = X4[idx];
        Pack4 p4;
        p4.h[0] = __float2half(v.x); p4.h[1] = __float2half(v.y);
        p4.h[2] = __float2half(v.z); p4.h[3] = __float2half(v.w);
        *(uint2*)&T[row * MPAD + col4 * 4] = p4.u;
    }
    int mm = lane & 15, quad = lane >> 4;
    short8 a[4];
#pragma unroll
    for (int ks = 0; ks < 4; ks++)
        a[ks] = *(const short8*)&T[mm * MPAD + ks * 32 + quad * 8];
    const short8* Bb = (const short8*)Wp + lane;
    f32x4 acc[8];
#pragma unroll
    for (int t = 0; t < 8; t++) acc[t] = (f32x4){0.f, 0.f, 0.f, 0.f};
#pragma unroll
    for (int ks = 0; ks < 4; ks++)
#pragma unroll
        for (int t = 0; t < 8; t++)
            acc[t] = __builtin_amdgcn_mfma_f32_16x16x32_f16(
                a[ks], Bb[(t * 4 + ks) * 64], acc[t], 0, 0, 0);
#pragma unroll
    for (int t = 0; t < 8; t++) {
        int n = t * 16 + mm;
        float bias = b[n];
#pragma unroll
        for (int r = 0; r < 4; r++) {
            int node = rt * 16 + quad * 4 + r;
            H[(size_t)node * 128 + n] = __float2half(fmaxf(acc[t][r] + bias, 0.f));
        }
    }
}

// ---------------------------------------------------------------------------
// K2: B planes (src-side pre-projection), f16 output. BN=0: input is hbuf
// (f16). BN=1: input is ybuf (fp32), applies BN+relu and writes hbuf (f16).
// ---------------------------------------------------------------------------
template<int BN>
__global__ __launch_bounds__(256) void k_preB(
    const __half* __restrict__ Xh, const float* __restrict__ Xf,
    const float* __restrict__ scale, const float* __restrict__ shift,
    __half* __restrict__ hout, const float* __restrict__ pre_W,
    int layer, __half* __restrict__ Bplanes) {
    __shared__ float Wb[2 * 4 * 32 * 32];  // 32 KB
    __shared__ float Xs[16 * 128];         // 8 KB
    int tid = threadIdx.x;
    for (int i = tid; i < 8192; i += 256) {
        int g = i & 31, f = (i >> 5) & 31, t = (i >> 10) & 3, r = i >> 12;
        Wb[i] = pre_W[((((layer * 2 + r) * 4 + t) * 64) + 32 + f) * 32 + g];
    }
    int r = tid >> 7, c = tid & 127, t = c >> 5, g = c & 31;
    const float* wp = &Wb[((r * 4 + t) * 32) * 32 + g];
    int base = blockIdx.x * 16;
    for (int i = tid; i < 16 * 128; i += 256) {
        int col = i & 127;
        size_t gi = (size_t)(base + (i >> 7)) * 128 + col;
        float v;
        if (BN) {
            v = fmaxf(scale[col] * Xf[gi] + shift[col], 0.f);
            hout[gi] = __float2half(v);
        } else {
            v = __half2float(Xh[gi]);
        }
        Xs[i] = v;
    }
    __syncthreads();
    for (int n = 0; n < 16; n++) {
        float acc = 0.f;
#pragma unroll
        for (int f = 0; f < 32; f++) acc += Xs[n * 128 + t * 32 + f] * wp[f * 32];
        Bplanes[(size_t)r * NN * 128 + (size_t)(base + n) * 128 + c] = __float2half(acc);
    }
}

// ---------------------------------------------------------------------------
// K3: FUSED gather+stats+MFMA-GEMM, pipelined over TPB tiles per block.
// Gather loads for tile i+1 are issued into registers BEFORE phase B of tile
// i, hiding L2/L3 gather latency behind the MFMA phase (vmcnt order: gathers
// issue first, B-frag waits imply their completion). 256-B-granule gather
// (16 lanes = 1 full neighbor row), XOR-swizzled Spack (0 conflicts).
// ---------------------------------------------------------------------------
__global__ __launch_bounds__(256) void k_agg_gemm(
    const __half* __restrict__ hbuf, const __half* __restrict__ Bplanes,
    const int* __restrict__ fwd_nbr, const int* __restrict__ rev_nbr,
    const __half* __restrict__ Wcp, const float* __restrict__ bc,
    float* __restrict__ Y, float* __restrict__ bnsum, float* __restrict__ bnsum2) {
    __shared__ __half Spack[KSTEPS * 64 * 8];  // 36,864 B
    __shared__ float bnred[256];
    int tid = threadIdx.x;
    bnred[tid] = 0.f;
    int lane = tid & 63, wv = tid >> 6;
    int s = lane >> 4, f16 = lane & 15;
    int tw = f16 >> 2, quad = f16 & 3;
    int m = wv * 4 + s;                 // dst slot (gather role)
    int fo = f16 * 8;                   // feature offset (halves)
    int pos = 16 * quad + (m ^ quad ^ ((tw & 1) << 2));
    int posx = 16 * s + (f16 ^ s ^ ((wv & 1) << 2));
    const __half* Bp1 = Bplanes + (size_t)NN * 128;
    int tbase = blockIdx.x * TPB;

    Pack8 raw0[8], raw1[8], xraw;
    auto issue = [&](int rt) {
        int rtc = rt < RT_CNT ? rt : RT_CNT - 1;
        int d = rtc * 16 + m;
        const int4* nf = (const int4*)&fwd_nbr[d * 8];
        const int4* nr = (const int4*)&rev_nbr[d * 8];
        int4 a0 = nf[0], a1 = nf[1], c0 = nr[0], c1 = nr[1];
        int i0[8] = {a0.x, a0.y, a0.z, a0.w, a1.x, a1.y, a1.z, a1.w};
        int i1[8] = {c0.x, c0.y, c0.z, c0.w, c1.x, c1.y, c1.z, c1.w};
#pragma unroll
        for (int k = 0; k < 8; k++)
            raw0[k].u = *(const uint4*)&Bplanes[(size_t)i0[k] * 128 + fo];
#pragma unroll
        for (int k = 0; k < 8; k++)
            raw1[k].u = *(const uint4*)&Bp1[(size_t)i1[k] * 128 + fo];
        xraw.u = *(const uint4*)&hbuf[(size_t)(rtc * 16 + f16) * 128 + wv * 32 + s * 8];
    };

    issue(tbase);
    int mB = lane & 15, qB = lane >> 4;
    int t0 = wv * 2;
    const short8* Bb = (const short8*)Wcp + lane;

#pragma unroll
    for (int i = 0; i < TPB; i++) {
        int rt = tbase + i;
        bool valid = rt < RT_CNT;
        // ---- stats -> Spack ----
#pragma unroll
        for (int rel = 0; rel < 2; rel++) {
            Pack8* rr = rel ? raw1 : raw0;
            float sS[8], qS[8], mnS[8], mxS[8];
#pragma unroll
            for (int j = 0; j < 8; j++) {
                sS[j] = 0.f; qS[j] = 0.f; mnS[j] = 1e30f; mxS[j] = -1e30f;
            }
#pragma unroll
            for (int k = 0; k < 8; k++) {
#pragma unroll
                for (int j2 = 0; j2 < 4; j2++) {
                    __half2 h = rr[k].h2[j2];
                    float a = __half2float(__low2half(h));
                    float b = __half2float(__high2half(h));
                    int j0 = 2 * j2, j1 = j0 + 1;
                    sS[j0] += a; qS[j0] += a * a;
                    mnS[j0] = fminf(mnS[j0], a); mxS[j0] = fmaxf(mxS[j0], a);
                    sS[j1] += b; qS[j1] += b * b;
                    mnS[j1] = fminf(mnS[j1], b); mxS[j1] = fmaxf(mxS[j1], b);
                }
            }
            Pack8 mean, stdv, mnp, mxp;
#pragma unroll
            for (int j = 0; j < 8; j++) {
                float Bm = sS[j] * 0.125f;
                mean.h[j] = __float2half(Bm);
                stdv.h[j] = __float2half(
                    sqrtf(fmaxf(qS[j] * 0.125f - Bm * Bm, 0.f) + 1e-5f));
                mnp.h[j] = __float2half(mnS[j]);
                mxp.h[j] = __float2half(mxS[j]);
            }
            int ksb = 4 + rel * 16 + tw * 4;
            *(uint4*)&Spack[((size_t)(ksb + 0) * 64 + pos) * 8] = mean.u;
            *(uint4*)&Spack[((size_t)(ksb + 1) * 64 + pos) * 8] = mnp.u;
            *(uint4*)&Spack[((size_t)(ksb + 2) * 64 + pos) * 8] = mxp.u;
            *(uint4*)&Spack[((size_t)(ksb + 3) * 64 + pos) * 8] = stdv.u;
        }
        *(uint4*)&Spack[((size_t)wv * 64 + posx) * 8] = xraw.u;
        __syncthreads();
        // ---- prefetch gathers for next tile (overlap with phase B) ----
        if (i + 1 < TPB) issue(rt + 1);
        // ---- phase B: MFMA, depth-6 B prefetch ----
        f32x4 acc0 = (f32x4){0.f, 0.f, 0.f, 0.f};
        f32x4 acc1 = (f32x4){0.f, 0.f, 0.f, 0.f};
        short8 p0[6], p1[6];
#pragma unroll
        for (int dd = 0; dd < 6; dd++) {
            p0[dd] = Bb[((size_t)t0 * KSTEPS + dd) * 64];
            p1[dd] = Bb[((size_t)(t0 + 1) * KSTEPS + dd) * 64];
        }
#pragma unroll
        for (int ks = 0; ks < KSTEPS; ks++) {
            int twk = (ks < 4) ? ks : (((ks - 4) >> 2) & 3);
            int posr = 16 * qB + (mB ^ qB ^ ((twk & 1) << 2));
            short8 a = *(const short8*)&Spack[((size_t)ks * 64 + posr) * 8];
            acc0 = __builtin_amdgcn_mfma_f32_16x16x32_f16(a, p0[ks % 6], acc0, 0, 0, 0);
            acc1 = __builtin_amdgcn_mfma_f32_16x16x32_f16(a, p1[ks % 6], acc1, 0, 0, 0);
            if (ks + 6 < KSTEPS) {
                p0[ks % 6] = Bb[((size_t)t0 * KSTEPS + ks + 6) * 64];
                p1[ks % 6] = Bb[((size_t)(t0 + 1) * KSTEPS + ks + 6) * 64];
            }
        }
        if (valid) {
#pragma unroll
            for (int tt = 0; tt < 2; tt++) {
                f32x4 acc = tt ? acc1 : acc0;
                int n = (t0 + tt) * 16 + mB;
                float bias = bc[n];
                float ls = 0.f, ls2 = 0.f;
#pragma unroll
                for (int r = 0; r < 4; r++) {
                    float v = acc[r] + bias;
                    int node = rt * 16 + qB * 4 + r;
                    Y[(size_t)node * 128 + n] = v;
                    ls += v; ls2 += v * v;
                }
                ls += __shfl_xor(ls, 16); ls += __shfl_xor(ls, 32);
                ls2 += __shfl_xor(ls2, 16); ls2 += __shfl_xor(ls2, 32);
                if (qB == 0) { bnred[n] += ls; bnred[128 + n] += ls2; }
            }
        }
        __syncthreads();
    }
    if (tid < 128) {
        atomicAdd(&bnsum[tid], bnred[tid]);
        atomicAdd(&bnsum2[tid], bnred[128 + tid]);
    }
}

// ---------------------------------------------------------------------------
// K5: BN finalize
// ---------------------------------------------------------------------------
__global__ void k_bn_final(const float* __restrict__ bnsum, const float* __restrict__ bnsum2,
                           const float* __restrict__ gamma, const float* __restrict__ beta,
                           int layer, float* __restrict__ scale, float* __restrict__ shift) {
    int c = threadIdx.x;
    float mu = bnsum[c] * (1.f / NN);
    float var = bnsum2[c] * (1.f / NN) - mu * mu;
    float sc = gamma[layer * 128 + c] * rsqrtf(var + 1e-5f);
    scale[c] = sc;
    shift[c] = beta[layer * 128 + c] - mu * sc;
}

// ---------------------------------------------------------------------------
// K7: fused BN+relu+MLP via MFMA (wave-private LDS, no barriers)
// ---------------------------------------------------------------------------
__global__ __launch_bounds__(256) void k_mlp_mfma(
    const float* __restrict__ Yb, const float* __restrict__ scale,
    const float* __restrict__ shift, const __half* __restrict__ W1p,
    const float* __restrict__ b1, const __half* __restrict__ W2p,
    const float* __restrict__ b2, float* __restrict__ out) {
    __shared__ __half Sh[4][16 * MPAD];
    int tid = threadIdx.x, wave = tid >> 6, lane = tid & 63;
    int rt = blockIdx.x * 4 + wave;
    if (rt >= RT_CNT) rt = RT_CNT - 1;  // redundant recompute, benign
    __half* T = Sh[wave];
    const float4* Y4 = (const float4*)Yb + (size_t)rt * 16 * 32;
    const float4* sc4 = (const float4*)scale;
    const float4* sh4 = (const float4*)shift;
#pragma unroll
    for (int i = 0; i < 8; i++) {
        int idx = i * 64 + lane;
        int row = idx >> 5, col4 = idx & 31;
        float4 v = Y4[idx];
        float4 s = sc4[col4], f = sh4[col4];
        Pack4 p4;
        p4.h[0] = __float2half(fmaxf(s.x * v.x + f.x, 0.f));
        p4.h[1] = __float2half(fmaxf(s.y * v.y + f.y, 0.f));
        p4.h[2] = __float2half(fmaxf(s.z * v.z + f.z, 0.f));
        p4.h[3] = __float2half(fmaxf(s.w * v.w + f.w, 0.f));
        *(uint2*)&T[row * MPAD + col4 * 4] = p4.u;
    }
    int mm = lane & 15, quad = lane >> 4;
    short8 a[4];
#pragma unroll
    for (int ks = 0; ks < 4; ks++)
        a[ks] = *(const short8*)&T[mm * MPAD + ks * 32 + quad * 8];
    const short8* B1 = (const short8*)W1p + lane;
    f32x4 acc[8];
#pragma unroll
    for (int t = 0; t < 8; t++) acc[t] = (f32x4){0.f, 0.f, 0.f, 0.f};
#pragma unroll
    for (int ks = 0; ks < 4; ks++)
#pragma unroll
        for (int t = 0; t < 8; t++)
            acc[t] = __builtin_amdgcn_mfma_f32_16x16x32_f16(
                a[ks], B1[(t * 4 + ks) * 64], acc[t], 0, 0, 0);
#pragma unroll
    for (int t = 0; t < 8; t++) {
        int n = t * 16 + mm;
        float bias = b1[n];
#pragma unroll
        for (int r = 0; r < 4; r++)
            T[(quad * 4 + r) * MPAD + n] = __float2half(fmaxf(acc[t][r] + bias, 0.f));
    }
    short8 a2[4];
#pragma unroll
    for (int ks = 0; ks < 4; ks++)
        a2[ks] = *(const short8*)&T[mm * MPAD + ks * 32 + quad * 8];
    const short8* B2 = (const short8*)W2p + lane;
    f32x4 acc2[2];
#pragma unroll
    for (int t = 0; t < 2; t++) acc2[t] = (f32x4){0.f, 0.f, 0.f, 0.f};
#pragma unroll
    for (int ks = 0; ks < 4; ks++)
#pragma unroll
        for (int t = 0; t < 2; t++)
            acc2[t] = __builtin_amdgcn_mfma_f32_16x16x32_f16(
                a2[ks], B2[(t * 4 + ks) * 64], acc2[t], 0, 0, 0);
#pragma unroll
    for (int t = 0; t < 2; t++) {
        int n = t * 16 + mm;
        float bias = b2[n];
#pragma unroll
        for (int r = 0; r < 4; r++)
            out[(size_t)(rt * 16 + quad * 4 + r) * 32 + n] = acc2[t][r] + bias;
    }
}

// ---------------------------------------------------------------------------
extern "C" void kernel_launch(void* const* d_in, const int* in_sizes, int n_in,
                              void* d_out, int out_size, void* d_ws, size_t ws_size,
                              hipStream_t stream) {
    const float* x      = (const float*)d_in[0];
    const float* W_in   = (const float*)d_in[1];
    const float* b_in   = (const float*)d_in[2];
    const float* pre_W  = (const float*)d_in[3];
    const float* pre_b  = (const float*)d_in[4];
    const float* post_W = (const float*)d_in[5];
    const float* post_b = (const float*)d_in[6];
    const float* lin_W  = (const float*)d_in[7];
    const float* lin_b  = (const float*)d_in[8];
    const float* bn_g   = (const float*)d_in[9];
    const float* bn_b   = (const float*)d_in[10];
    const float* mlp_W1 = (const float*)d_in[11];
    const float* mlp_b1 = (const float*)d_in[12];
    const float* mlp_W2 = (const float*)d_in[13];
    const float* mlp_b2 = (const float*)d_in[14];
    const int*   edge   = (const int*)d_in[15];
    float* out = (float*)d_out;

    char* w = (char*)d_ws;
    const size_t plane = (size_t)NN * 128 * sizeof(float);       // 25.6 MB
    __half* hbuf = (__half*)w; w += plane / 2;                   // f16 now
    float* ybuf = (float*)w; w += plane;
    __half* Bpl = (__half*)w; w += plane;                        // both rels, f16
    int* fwd_nbr = (int*)w; w += (size_t)NN * DEG * sizeof(int);
    int* rev_nbr = (int*)w; w += (size_t)NN * DEG * sizeof(int);
    int* cnt     = (int*)w; w += (size_t)2 * NN * sizeof(int);
    float* Qw    = (float*)w; w += (size_t)2 * 128 * 128 * sizeof(float);
    float* bc    = (float*)w; w += 2 * 128 * sizeof(float);      // adjacent to Qw
    __half* Wcp  = (__half*)w; w += (size_t)2 * KSTEPS * 32 * 128 * sizeof(__half);
    __half* Winp = (__half*)w; w += (size_t)128 * 128 * sizeof(__half);
    __half* W1p  = (__half*)w; w += (size_t)128 * 128 * sizeof(__half);
    __half* W2p  = (__half*)w; w += (size_t)128 * 32 * sizeof(__half);
    float* bnsum  = (float*)w; w += 128 * sizeof(float);
    float* bnsum2 = (float*)w; w += 128 * sizeof(float);
    float* scale  = (float*)w; w += 128 * sizeof(float);
    float* shift  = (float*)w; w += 128 * sizeof(float);

    const int gWave = (RT_CNT + 3) / 4;   // 782 blocks (4 waves each)
    const int gAgg  = (RT_CNT + TPB - 1) / TPB;  // 782 pipelined blocks

    (void)hipMemsetAsync(cnt, 0, (size_t)2 * NN * sizeof(int), stream);
    (void)hipMemsetAsync(Qw, 0, (size_t)(2 * 128 * 128 + 2 * 128) * sizeof(float), stream);
    k_build_nbr<<<(EE + 255) / 256, 256, 0, stream>>>(edge, cnt, fwd_nbr, rev_nbr);
    k_wprep<<<16, 256, 0, stream>>>(post_W, pre_W, pre_b, post_b, lin_W, lin_b,
                                    Wcp, Qw, bc);
    k_pack_xt<<<16, 256, 0, stream>>>(Qw, Wcp);
    k_pack_b<<<8, 256, 0, stream>>>(W_in, 128, 128, Winp);
    k_pack_b<<<8, 256, 0, stream>>>(mlp_W1, 128, 128, W1p);
    k_pack_b<<<2, 256, 0, stream>>>(mlp_W2, 128, 32, W2p);

    // h = relu(x @ W_in + b_in)  (MFMA, f16 out)
    k_in_mfma<<<gWave, 256, 0, stream>>>(x, Winp, b_in, hbuf);

    for (int l = 0; l < 2; l++) {
        if (l == 0)
            k_preB<0><<<RT_CNT, 256, 0, stream>>>(hbuf, nullptr, nullptr, nullptr,
                                                  nullptr, pre_W, 0, Bpl);
        else  // fused: h1 = relu(bn(y0)) -> hbuf (f16), plus B planes
            k_preB<1><<<RT_CNT, 256, 0, stream>>>(nullptr, ybuf, scale, shift,
                                                  hbuf, pre_W, 1, Bpl);
        (void)hipMemsetAsync(bnsum, 0, 2 * 128 * sizeof(float), stream);
        k_agg_gemm<<<gAgg, 256, 0, stream>>>(
            hbuf, Bpl, fwd_nbr, rev_nbr, Wcp + (size_t)l * KSTEPS * 32 * 128,
            bc + l * 128, ybuf, bnsum, bnsum2);
        k_bn_final<<<1, 128, 0, stream>>>(bnsum, bnsum2, bn_g, bn_b, l, scale, shift);
    }

    // out = relu(bn_relu(y) @ mlp_W1 + b1) @ mlp_W2 + b2   (fused, MFMA)
    k_mlp_mfma<<<gWave, 256, 0, stream>>>(ybuf, scale, shift, W1p, mlp_b1,
                                          W2p, mlp_b2, out);
}

// Round 12
// 456.665 us; speedup vs baseline: 1.0874x; 1.0874x over previous
//
#include <hip/hip_runtime.h>
#include <hip/hip_fp16.h>
#include <cstddef>
#include <cstdint>

#define NN 50000
#define DEG 8
#define EE (NN*DEG)
#define RT_CNT 3125   // NN/16 row-tiles
#define KSTEPS 36     // K=1152 / 32:  [xt(4) | rel*16+tw*4+{Bm,mn,mx,std}]
#define W8L 18432     // Wcp layer stride in short8 units (KSTEPS*32*128/8)
#define MPAD 132      // f16 tile row pad (halves)

typedef __attribute__((ext_vector_type(8))) short short8;
typedef __attribute__((ext_vector_type(4))) float f32x4;

union Pack8 { __half h[8]; __half2 h2[4]; uint4 u; short8 s8; };

// ---------------------------------------------------------------------------
// K0: build neighbor lists (constant degree 8) via atomic counters
// ---------------------------------------------------------------------------
__global__ void k_build_nbr(const int* __restrict__ ef, int* __restrict__ cnt,
                            int* __restrict__ fwd_nbr, int* __restrict__ rev_nbr) {
    int e = blockIdx.x * blockDim.x + threadIdx.x;
    if (e >= EE) return;
    int s = ef[e], d = ef[EE + e];
    int p = atomicAdd(&cnt[d], 1);
    fwd_nbr[d * DEG + p] = s;
    int q = atomicAdd(&cnt[NN + s], 1);
    rev_nbr[s * DEG + q] = d;
}

// ---------------------------------------------------------------------------
// K0w: combined-weight prep (unchanged from R10)
// ---------------------------------------------------------------------------
__global__ __launch_bounds__(256) void k_wprep(
    const float* __restrict__ post_W, const float* __restrict__ pre_W,
    const float* __restrict__ pre_b, const float* __restrict__ post_b,
    const float* __restrict__ lin_W, const float* __restrict__ lin_b,
    __half* __restrict__ Wcp, float* __restrict__ Qw, float* __restrict__ bc) {
    __shared__ float Pf[160 * 33];
    __shared__ float Wl[32 * 128];
    __shared__ float Wt[32 * 32];
    __shared__ float Ps[32 * 32];
    __shared__ float Q[32 * 32];
    __shared__ float T3s[32];
    int tid = threadIdx.x;
    int m4 = blockIdx.x;
    int l = m4 >> 3, r = (m4 >> 2) & 1, tw = m4 & 3;
    const float* PW = post_W + (size_t)m4 * 416 * 32;
    for (int i = tid; i < 160 * 32; i += 256) {
        int row = i >> 5, g = i & 31;
        float v;
        if (row < 32) v = PW[row * 32 + g];
        else {
            int rr = row - 32;
            v = PW[(32 + rr) * 32 + g] + PW[(160 + rr) * 32 + g] + PW[(288 + rr) * 32 + g];
        }
        Pf[row * 33 + g] = v;
    }
    for (int i = tid; i < 1024; i += 256) Wt[i] = pre_W[(size_t)m4 * 2048 + i];
    for (int i = tid; i < 4096; i += 256)
        Wl[i] = lin_W[(size_t)(l * 2 + r) * 16384 + tw * 32 * 128 + i];
    __syncthreads();
    for (int i = tid; i < 1024; i += 256) {
        int g = i >> 5, j = i & 31;
        Ps[i] = Pf[(32 + g) * 33 + j] + Pf[(64 + g) * 33 + j] + Pf[(96 + g) * 33 + j];
    }
    __syncthreads();
    for (int i = tid; i < 1024; i += 256) {
        int f = i >> 5, j = i & 31;
        float acc = Pf[f * 33 + j];
#pragma unroll
        for (int g = 0; g < 32; g++) acc += Wt[f * 32 + g] * Ps[g * 32 + j];
        Q[i] = acc;
    }
    if (tid < 32) {
        int j = tid;
        float v = post_b[m4 * 32 + j];
#pragma unroll
        for (int g = 0; g < 32; g++) v += pre_b[m4 * 32 + g] * Ps[g * 32 + j];
        T3s[j] = v;
    }
    __syncthreads();
    for (int u = tid; u < 2048; u += 256) {
        int lane = u & 63, t = (u >> 6) & 7, s = u >> 9;
        int quad = lane >> 4, nl = lane & 15;
        int n = t * 16 + nl;
        Pack8 pk;
#pragma unroll
        for (int e = 0; e < 8; e++) {
            int f = quad * 8 + e;
            const float* Pr = &Pf[((s + 1) * 32 + f) * 33];
            float acc = 0.f;
#pragma unroll
            for (int j = 0; j < 32; j++) acc += Pr[j] * Wl[j * 128 + n];
            pk.h[e] = __float2half(acc);
        }
        int ks = 4 + r * 16 + tw * 4 + s;
        *(uint4*)&Wcp[((size_t)l * W8L + (t * KSTEPS + ks) * 64 + lane) * 8] = pk.u;
    }
    for (int i = tid; i < 4096; i += 256) {
        int f = i >> 7, n = i & 127;
        float acc = 0.f;
#pragma unroll
        for (int j = 0; j < 32; j++) acc += Q[f * 32 + j] * Wl[j * 128 + n];
        atomicAdd(&Qw[(size_t)l * 16384 + (tw * 32 + f) * 128 + n], acc);
    }
    if (tid < 128) {
        float v = 0.f;
#pragma unroll
        for (int j = 0; j < 32; j++) v += T3s[j] * Wl[j * 128 + tid];
        atomicAdd(&bc[l * 128 + tid], v);
        if ((m4 & 7) == 0)
            atomicAdd(&bc[l * 128 + tid],
                      lin_b[(2 * l) * 128 + tid] + lin_b[(2 * l + 1) * 128 + tid]);
    }
}

// ---------------------------------------------------------------------------
// K0x: pack xt rows (Qw fp32) into Wcp f16 B-frag layout (ks = tw in [0,4))
// ---------------------------------------------------------------------------
__global__ void k_pack_xt(const float* __restrict__ Qw, __half* __restrict__ Wcp) {
    int gid = blockIdx.x * blockDim.x + threadIdx.x;
    if (gid >= 2 * 4 * 8 * 64) return;
    int lane = gid & 63, t = (gid >> 6) & 7, ks = (gid >> 9) & 3, l = gid >> 11;
    int quad = lane >> 4;
    int n = t * 16 + (lane & 15);
    Pack8 pk;
#pragma unroll
    for (int e = 0; e < 8; e++)
        pk.h[e] = __float2half(Qw[(size_t)l * 16384 + (ks * 32 + quad * 8 + e) * 128 + n]);
    *(uint4*)&Wcp[((size_t)l * W8L + (t * KSTEPS + ks) * 64 + lane) * 8] = pk.u;
}

// ---------------------------------------------------------------------------
// K0y: generic fp32 [K][N] -> f16 MFMA-B-frag pack
// ---------------------------------------------------------------------------
__global__ void k_pack_b(const float* __restrict__ W, int K, int N,
                         __half* __restrict__ dst) {
    int gid = blockIdx.x * blockDim.x + threadIdx.x;
    int total = (K >> 5) * (N >> 4) * 64;
    if (gid >= total) return;
    int lane = gid & 63;
    int ks = (gid >> 6) % (K >> 5);
    int t = (gid >> 6) / (K >> 5);
    int quad = lane >> 4, nl = lane & 15;
    int n = t * 16 + nl;
    Pack8 pk;
#pragma unroll
    for (int e = 0; e < 8; e++)
        pk.h[e] = __float2half(W[(size_t)(ks * 32 + quad * 8 + e) * N + n]);
    *(uint4*)&dst[(size_t)gid * 8] = pk.u;
}

// ---------------------------------------------------------------------------
// K0z: pack block-diagonal pre_W-bottom into B-frag f16: WbBD[l][rel][128][128]
// nonzero iff k and n in the same tower: val = pre_W[m4][32+f][g]
// ---------------------------------------------------------------------------
__global__ void k_pack_wbd(const float* __restrict__ pre_W, __half* __restrict__ dst) {
    int gid = blockIdx.x * blockDim.x + threadIdx.x;
    if (gid >= 2 * 2 * 8 * 4 * 64) return;
    int lane = gid & 63, ks = (gid >> 6) & 3, t8 = (gid >> 8) & 7;
    int rel = (gid >> 11) & 1, l = gid >> 12;
    int quad = lane >> 4, nl = lane & 15;
    int n = t8 * 16 + nl;
    int tn = n >> 5;
    Pack8 pk;
#pragma unroll
    for (int e = 0; e < 8; e++) {
        int k = ks * 32 + quad * 8 + e;
        float v = 0.f;
        if ((k >> 5) == tn)
            v = pre_W[(size_t)((((l * 2 + rel) * 4 + tn) * 64) + 32 + (k & 31)) * 32 + (n & 31)];
        pk.h[e] = __float2half(v);
    }
    *(uint4*)&dst[((size_t)(l * 2 + rel) * 2048 + (t8 * 4 + ks) * 64 + lane) * 8] = pk.u;
}

// ---------------------------------------------------------------------------
// K1: input layer via MFMA: h = relu(x @ W_in + b_in), f16 out. A-frags read
// directly from global x; C staged via wave-private LDS tile -> coalesced
// 1-KB stores. No barriers.
// ---------------------------------------------------------------------------
__global__ __launch_bounds__(256) void k_in_mfma(
    const float* __restrict__ X, const __half* __restrict__ Wp,
    const float* __restrict__ b, __half* __restrict__ H) {
    __shared__ __half Sh[4][16 * MPAD];
    int tid = threadIdx.x, wv = tid >> 6, lane = tid & 63;
    int rt = blockIdx.x * 4 + wv;
    if (rt >= RT_CNT) rt = RT_CNT - 1;  // duplicate work, benign
    int mm = lane & 15, quad = lane >> 4;
    short8 a[4];
#pragma unroll
    for (int ks = 0; ks < 4; ks++) {
        const float4* p = (const float4*)&X[(size_t)(rt * 16 + mm) * 128 + ks * 32 + quad * 8];
        float4 v0 = p[0], v1 = p[1];
        Pack8 pk;
        pk.h[0] = __float2half(v0.x); pk.h[1] = __float2half(v0.y);
        pk.h[2] = __float2half(v0.z); pk.h[3] = __float2half(v0.w);
        pk.h[4] = __float2half(v1.x); pk.h[5] = __float2half(v1.y);
        pk.h[6] = __float2half(v1.z); pk.h[7] = __float2half(v1.w);
        a[ks] = pk.s8;
    }
    const short8* Bb = (const short8*)Wp + lane;
    f32x4 acc[8];
#pragma unroll
    for (int t = 0; t < 8; t++) acc[t] = (f32x4){0.f, 0.f, 0.f, 0.f};
#pragma unroll
    for (int ks = 0; ks < 4; ks++)
#pragma unroll
        for (int t = 0; t < 8; t++)
            acc[t] = __builtin_amdgcn_mfma_f32_16x16x32_f16(
                a[ks], Bb[(t * 4 + ks) * 64], acc[t], 0, 0, 0);
    __half* T = Sh[wv];
#pragma unroll
    for (int t = 0; t < 8; t++) {
        int n = t * 16 + mm;
        float bias = b[n];
#pragma unroll
        for (int r = 0; r < 4; r++)
            T[(quad * 4 + r) * MPAD + n] = __float2half(fmaxf(acc[t][r] + bias, 0.f));
    }
#pragma unroll
    for (int it = 0; it < 4; it++) {
        int idx = it * 64 + lane;
        int row = idx >> 4, col = (idx & 15) * 8;
        *(uint4*)&H[(size_t)(rt * 16 + row) * 128 + col] = *(uint4*)&T[row * MPAD + col];
    }
}

// ---------------------------------------------------------------------------
// K2: B planes via MFMA vs block-diag packed pre_W (WbBD). V=1: input hbuf
// f16 (A-frags = direct uint4 copies). V=2: input ybuf fp32 + inline BN
// finalize + relu; writes hbuf f16 A-frag chunks directly.
// ---------------------------------------------------------------------------
template<int V>
__global__ __launch_bounds__(256) void k_preB_mfma(
    const __half* __restrict__ Hin, const float* __restrict__ Yf,
    const float* __restrict__ bns, const float* __restrict__ bns2,
    const float* __restrict__ gamma, const float* __restrict__ beta,
    __half* __restrict__ Hout, const __half* __restrict__ WbBDp,
    __half* __restrict__ Bplanes) {
    __shared__ __half Sh[4][16 * MPAD];
    __shared__ float sc[128], sh[128];
    int tid = threadIdx.x, wv = tid >> 6, lane = tid & 63;
    int rt = blockIdx.x * 4 + wv;
    if (rt >= RT_CNT) rt = RT_CNT - 1;
    if (V == 2) {
        if (tid < 128) {
            float mu = bns[tid] * (1.f / NN);
            float var = bns2[tid] * (1.f / NN) - mu * mu;
            float s = gamma[tid] * rsqrtf(var + 1e-5f);
            sc[tid] = s;
            sh[tid] = beta[tid] - mu * s;
        }
        __syncthreads();
    }
    int mm = lane & 15, quad = lane >> 4;
    short8 a[4];
#pragma unroll
    for (int ks = 0; ks < 4; ks++) {
        int c0 = ks * 32 + quad * 8;
        size_t base = (size_t)(rt * 16 + mm) * 128 + c0;
        if (V == 1) {
            Pack8 pk; pk.u = *(const uint4*)&Hin[base];
            a[ks] = pk.s8;
        } else {
            const float4* p = (const float4*)&Yf[base];
            float4 v0 = p[0], v1 = p[1];
            float4 s0 = *(const float4*)&sc[c0], s1 = *(const float4*)&sc[c0 + 4];
            float4 f0 = *(const float4*)&sh[c0], f1 = *(const float4*)&sh[c0 + 4];
            Pack8 pk;
            pk.h[0] = __float2half(fmaxf(s0.x * v0.x + f0.x, 0.f));
            pk.h[1] = __float2half(fmaxf(s0.y * v0.y + f0.y, 0.f));
            pk.h[2] = __float2half(fmaxf(s0.z * v0.z + f0.z, 0.f));
            pk.h[3] = __float2half(fmaxf(s0.w * v0.w + f0.w, 0.f));
            pk.h[4] = __float2half(fmaxf(s1.x * v1.x + f1.x, 0.f));
            pk.h[5] = __float2half(fmaxf(s1.y * v1.y + f1.y, 0.f));
            pk.h[6] = __float2half(fmaxf(s1.z * v1.z + f1.z, 0.f));
            pk.h[7] = __float2half(fmaxf(s1.w * v1.w + f1.w, 0.f));
            *(uint4*)&Hout[base] = pk.u;
            a[ks] = pk.s8;
        }
    }
    __half* T = Sh[wv];
#pragma unroll
    for (int rel = 0; rel < 2; rel++) {
        const short8* Bb = (const short8*)WbBDp + (size_t)rel * 2048 + lane;
        f32x4 acc[8];
#pragma unroll
        for (int t = 0; t < 8; t++) acc[t] = (f32x4){0.f, 0.f, 0.f, 0.f};
#pragma unroll
        for (int ks = 0; ks < 4; ks++)
#pragma unroll
            for (int t = 0; t < 8; t++)
                acc[t] = __builtin_amdgcn_mfma_f32_16x16x32_f16(
                    a[ks], Bb[(t * 4 + ks) * 64], acc[t], 0, 0, 0);
#pragma unroll
        for (int t = 0; t < 8; t++) {
            int n = t * 16 + mm;
#pragma unroll
            for (int r = 0; r < 4; r++)
                T[(quad * 4 + r) * MPAD + n] = __float2half(acc[t][r]);
        }
        __half* Bp = Bplanes + (size_t)rel * NN * 128;
#pragma unroll
        for (int it = 0; it < 4; it++) {
            int idx = it * 64 + lane;
            int row = idx >> 4, col = (idx & 15) * 8;
            *(uint4*)&Bp[(size_t)(rt * 16 + row) * 128 + col] = *(uint4*)&T[row * MPAD + col];
        }
    }
}

// ---------------------------------------------------------------------------
// K3: FUSED gather+stats+MFMA-GEMM (R10 structure: 1 tile/block, grid 3125).
// 256-B-granule gather, XOR-swizzled Spack (0 conflicts), depth-6 B prefetch.
// ---------------------------------------------------------------------------
__global__ __launch_bounds__(256, 4) void k_agg_gemm(
    const __half* __restrict__ hbuf, const __half* __restrict__ Bplanes,
    const int* __restrict__ fwd_nbr, const int* __restrict__ rev_nbr,
    const __half* __restrict__ Wcp, const float* __restrict__ bc,
    float* __restrict__ Y, float* __restrict__ bnsum, float* __restrict__ bnsum2) {
    __shared__ __half Spack[KSTEPS * 64 * 8];  // 36,864 B
    __shared__ float bnred[256];
    int tid = threadIdx.x;
    int blk = blockIdx.x;
    bnred[tid] = 0.f;
    int lane = tid & 63, wv = tid >> 6;
    int s = lane >> 4, f16 = lane & 15;
    int tw = f16 >> 2, quad = f16 & 3;
    int m = wv * 4 + s;
    int d = blk * 16 + m;
    // ---- Phase A: gather (256-B granule) + in-lane stats ----
    {
        const int4* nf = (const int4*)&fwd_nbr[d * 8];
        const int4* nr = (const int4*)&rev_nbr[d * 8];
        int4 a0 = nf[0], a1 = nf[1], b0v = nr[0], b1v = nr[1];
        int idx0[8] = {a0.x, a0.y, a0.z, a0.w, a1.x, a1.y, a1.z, a1.w};
        int idx1[8] = {b0v.x, b0v.y, b0v.z, b0v.w, b1v.x, b1v.y, b1v.z, b1v.w};
        int fo = f16 * 8;
        Pack8 r0[8], r1[8];
        const __half* Bp1 = Bplanes + (size_t)NN * 128;
#pragma unroll
        for (int k = 0; k < 8; k++)
            r0[k].u = *(const uint4*)&Bplanes[(size_t)idx0[k] * 128 + fo];
#pragma unroll
        for (int k = 0; k < 8; k++)
            r1[k].u = *(const uint4*)&Bp1[(size_t)idx1[k] * 128 + fo];
        // xt row (ks = wv): logical (node=f16, octet=s), f16 direct copy
        Pack8 xr;
        xr.u = *(const uint4*)&hbuf[(size_t)(blk * 16 + f16) * 128 + wv * 32 + s * 8];
        int pos = 16 * quad + (m ^ quad ^ ((tw & 1) << 2));
#pragma unroll
        for (int rel = 0; rel < 2; rel++) {
            Pack8* rr = rel ? r1 : r0;
            float sS[8], qS[8], mnS[8], mxS[8];
#pragma unroll
            for (int j = 0; j < 8; j++) {
                sS[j] = 0.f; qS[j] = 0.f; mnS[j] = 1e30f; mxS[j] = -1e30f;
            }
#pragma unroll
            for (int k = 0; k < 8; k++) {
#pragma unroll
                for (int j2 = 0; j2 < 4; j2++) {
                    __half2 h = rr[k].h2[j2];
                    float a = __half2float(__low2half(h));
                    float b = __half2float(__high2half(h));
                    int j0 = 2 * j2, j1 = j0 + 1;
                    sS[j0] += a; qS[j0] += a * a;
                    mnS[j0] = fminf(mnS[j0], a); mxS[j0] = fmaxf(mxS[j0], a);
                    sS[j1] += b; qS[j1] += b * b;
                    mnS[j1] = fminf(mnS[j1], b); mxS[j1] = fmaxf(mxS[j1], b);
                }
            }
            Pack8 mean, stdv, mnp, mxp;
#pragma unroll
            for (int j = 0; j < 8; j++) {
                float Bm = sS[j] * 0.125f;
                mean.h[j] = __float2half(Bm);
                stdv.h[j] = __float2half(
                    sqrtf(fmaxf(qS[j] * 0.125f - Bm * Bm, 0.f) + 1e-5f));
                mnp.h[j] = __float2half(mnS[j]);
                mxp.h[j] = __float2half(mxS[j]);
            }
            int ksb = 4 + rel * 16 + tw * 4;
            *(uint4*)&Spack[((size_t)(ksb + 0) * 64 + pos) * 8] = mean.u;
            *(uint4*)&Spack[((size_t)(ksb + 1) * 64 + pos) * 8] = mnp.u;
            *(uint4*)&Spack[((size_t)(ksb + 2) * 64 + pos) * 8] = mxp.u;
            *(uint4*)&Spack[((size_t)(ksb + 3) * 64 + pos) * 8] = stdv.u;
        }
        int posx = 16 * s + (f16 ^ s ^ ((wv & 1) << 2));
        *(uint4*)&Spack[((size_t)wv * 64 + posx) * 8] = xr.u;
    }
    __syncthreads();
    // ---- Phase B: MFMA with depth-6 B prefetch ----
    int mB = lane & 15, qB = lane >> 4;
    int t0 = wv * 2;
    const short8* Bb = (const short8*)Wcp + lane;
    f32x4 acc0 = (f32x4){0.f, 0.f, 0.f, 0.f};
    f32x4 acc1 = (f32x4){0.f, 0.f, 0.f, 0.f};
    short8 p0[6], p1[6];
#pragma unroll
    for (int dd = 0; dd < 6; dd++) {
        p0[dd] = Bb[((size_t)t0 * KSTEPS + dd) * 64];
        p1[dd] = Bb[((size_t)(t0 + 1) * KSTEPS + dd) * 64];
    }
#pragma unroll
    for (int ks = 0; ks < KSTEPS; ks++) {
        int twk = (ks < 4) ? ks : (((ks - 4) >> 2) & 3);
        int posr = 16 * qB + (mB ^ qB ^ ((twk & 1) << 2));
        short8 a = *(const short8*)&Spack[((size_t)ks * 64 + posr) * 8];
        acc0 = __builtin_amdgcn_mfma_f32_16x16x32_f16(a, p0[ks % 6], acc0, 0, 0, 0);
        acc1 = __builtin_amdgcn_mfma_f32_16x16x32_f16(a, p1[ks % 6], acc1, 0, 0, 0);
        if (ks + 6 < KSTEPS) {
            p0[ks % 6] = Bb[((size_t)t0 * KSTEPS + ks + 6) * 64];
            p1[ks % 6] = Bb[((size_t)(t0 + 1) * KSTEPS + ks + 6) * 64];
        }
    }
#pragma unroll
    for (int tt = 0; tt < 2; tt++) {
        f32x4 acc = tt ? acc1 : acc0;
        int n = (t0 + tt) * 16 + mB;
        float bias = bc[n];
        float ls = 0.f, ls2 = 0.f;
#pragma unroll
        for (int r = 0; r < 4; r++) {
            float v = acc[r] + bias;
            int node = blk * 16 + qB * 4 + r;
            Y[(size_t)node * 128 + n] = v;
            ls += v; ls2 += v * v;
        }
        ls += __shfl_xor(ls, 16); ls += __shfl_xor(ls, 32);
        ls2 += __shfl_xor(ls2, 16); ls2 += __shfl_xor(ls2, 32);
        if (qB == 0) { bnred[n] += ls; bnred[128 + n] += ls2; }
    }
    __syncthreads();
    if (tid < 128) {
        atomicAdd(&bnsum[tid], bnred[tid]);
        atomicAdd(&bnsum2[tid], bnred[128 + tid]);
    }
}

// ---------------------------------------------------------------------------
// K7: fused BN(inline finalize)+relu+MLP via MFMA
// ---------------------------------------------------------------------------
__global__ __launch_bounds__(256) void k_mlp_mfma(
    const float* __restrict__ Yb, const float* __restrict__ bns,
    const float* __restrict__ bns2, const float* __restrict__ gamma,
    const float* __restrict__ beta, const __half* __restrict__ W1p,
    const float* __restrict__ b1, const __half* __restrict__ W2p,
    const float* __restrict__ b2, float* __restrict__ out) {
    __shared__ __half Sh[4][16 * MPAD];
    __shared__ float sc[128], sh[128];
    int tid = threadIdx.x, wv = tid >> 6, lane = tid & 63;
    int rt = blockIdx.x * 4 + wv;
    if (rt >= RT_CNT) rt = RT_CNT - 1;
    if (tid < 128) {
        float mu = bns[tid] * (1.f / NN);
        float var = bns2[tid] * (1.f / NN) - mu * mu;
        float s = gamma[tid] * rsqrtf(var + 1e-5f);
        sc[tid] = s;
        sh[tid] = beta[tid] - mu * s;
    }
    __syncthreads();
    int mm = lane & 15, quad = lane >> 4;
    short8 a[4];
#pragma unroll
    for (int ks = 0; ks < 4; ks++) {
        int c0 = ks * 32 + quad * 8;
        const float4* p = (const float4*)&Yb[(size_t)(rt * 16 + mm) * 128 + c0];
        float4 v0 = p[0], v1 = p[1];
        float4 s0 = *(const float4*)&sc[c0], s1 = *(const float4*)&sc[c0 + 4];
        float4 f0 = *(const float4*)&sh[c0], f1 = *(const float4*)&sh[c0 + 4];
        Pack8 pk;
        pk.h[0] = __float2half(fmaxf(s0.x * v0.x + f0.x, 0.f));
        pk.h[1] = __float2half(fmaxf(s0.y * v0.y + f0.y, 0.f));
        pk.h[2] = __float2half(fmaxf(s0.z * v0.z + f0.z, 0.f));
        pk.h[3] = __float2half(fmaxf(s0.w * v0.w + f0.w, 0.f));
        pk.h[4] = __float2half(fmaxf(s1.x * v1.x + f1.x, 0.f));
        pk.h[5] = __float2half(fmaxf(s1.y * v1.y + f1.y, 0.f));
        pk.h[6] = __float2half(fmaxf(s1.z * v1.z + f1.z, 0.f));
        pk.h[7] = __float2half(fmaxf(s1.w * v1.w + f1.w, 0.f));
        a[ks] = pk.s8;
    }
    const short8* B1 = (const short8*)W1p + lane;
    f32x4 acc[8];
#pragma unroll
    for (int t = 0; t < 8; t++) acc[t] = (f32x4){0.f, 0.f, 0.f, 0.f};
#pragma unroll
    for (int ks = 0; ks < 4; ks++)
#pragma unroll
        for (int t = 0; t < 8; t++)
            acc[t] = __builtin_amdgcn_mfma_f32_16x16x32_f16(
                a[ks], B1[(t * 4 + ks) * 64], acc[t], 0, 0, 0);
    __half* T = Sh[wv];
#pragma unroll
    for (int t = 0; t < 8; t++) {
        int n = t * 16 + mm;
        float bias = b1[n];
#pragma unroll
        for (int r = 0; r < 4; r++)
            T[(quad * 4 + r) * MPAD + n] = __float2half(fmaxf(acc[t][r] + bias, 0.f));
    }
    short8 a2[4];
#pragma unroll
    for (int ks = 0; ks < 4; ks++)
        a2[ks] = *(const short8*)&T[mm * MPAD + ks * 32 + quad * 8];
    const short8* B2 = (const short8*)W2p + lane;
    f32x4 acc2[2];
#pragma unroll
    for (int t = 0; t < 2; t++) acc2[t] = (f32x4){0.f, 0.f, 0.f, 0.f};
#pragma unroll
    for (int ks = 0; ks < 4; ks++)
#pragma unroll
        for (int t = 0; t < 2; t++)
            acc2[t] = __builtin_amdgcn_mfma_f32_16x16x32_f16(
                a2[ks], B2[(t * 4 + ks) * 64], acc2[t], 0, 0, 0);
#pragma unroll
    for (int t = 0; t < 2; t++) {
        int n = t * 16 + mm;
        float bias = b2[n];
#pragma unroll
        for (int r = 0; r < 4; r++)
            out[(size_t)(rt * 16 + quad * 4 + r) * 32 + n] = acc2[t][r] + bias;
    }
}

// ---------------------------------------------------------------------------
extern "C" void kernel_launch(void* const* d_in, const int* in_sizes, int n_in,
                              void* d_out, int out_size, void* d_ws, size_t ws_size,
                              hipStream_t stream) {
    const float* x      = (const float*)d_in[0];
    const float* W_in   = (const float*)d_in[1];
    const float* b_in   = (const float*)d_in[2];
    const float* pre_W  = (const float*)d_in[3];
    const float* pre_b  = (const float*)d_in[4];
    const float* post_W = (const float*)d_in[5];
    const float* post_b = (const float*)d_in[6];
    const float* lin_W  = (const float*)d_in[7];
    const float* lin_b  = (const float*)d_in[8];
    const float* bn_g   = (const float*)d_in[9];
    const float* bn_b   = (const float*)d_in[10];
    const float* mlp_W1 = (const float*)d_in[11];
    const float* mlp_b1 = (const float*)d_in[12];
    const float* mlp_W2 = (const float*)d_in[13];
    const float* mlp_b2 = (const float*)d_in[14];
    const int*   edge   = (const int*)d_in[15];
    float* out = (float*)d_out;

    char* w = (char*)d_ws;
    const size_t plane = (size_t)NN * 128 * sizeof(float);       // 25.6 MB
    __half* hbuf = (__half*)w; w += plane / 2;                   // f16
    float* ybuf = (float*)w; w += plane;
    __half* Bpl = (__half*)w; w += plane;                        // both rels, f16
    int* fwd_nbr = (int*)w; w += (size_t)NN * DEG * sizeof(int);
    int* rev_nbr = (int*)w; w += (size_t)NN * DEG * sizeof(int);
    int* cnt     = (int*)w; w += (size_t)2 * NN * sizeof(int);
    float* Qw    = (float*)w; w += (size_t)2 * 128 * 128 * sizeof(float);
    float* bc    = (float*)w; w += 2 * 128 * sizeof(float);      // adjacent to Qw
    __half* Wcp  = (__half*)w; w += (size_t)2 * KSTEPS * 32 * 128 * sizeof(__half);
    __half* Winp = (__half*)w; w += (size_t)128 * 128 * sizeof(__half);
    __half* W1p  = (__half*)w; w += (size_t)128 * 128 * sizeof(__half);
    __half* W2p  = (__half*)w; w += (size_t)128 * 32 * sizeof(__half);
    __half* WbBD = (__half*)w; w += (size_t)4 * 128 * 128 * sizeof(__half);
    float* bns   = (float*)w; w += 4 * 128 * sizeof(float);  // pairs: l0(s,s2), l1(s,s2)

    const int gWave = (RT_CNT + 3) / 4;  // 782 blocks, 4 waves each

    (void)hipMemsetAsync(cnt, 0, (size_t)2 * NN * sizeof(int), stream);
    (void)hipMemsetAsync(Qw, 0, (size_t)(2 * 128 * 128 + 2 * 128) * sizeof(float), stream);
    (void)hipMemsetAsync(bns, 0, 4 * 128 * sizeof(float), stream);
    k_build_nbr<<<(EE + 255) / 256, 256, 0, stream>>>(edge, cnt, fwd_nbr, rev_nbr);
    k_wprep<<<16, 256, 0, stream>>>(post_W, pre_W, pre_b, post_b, lin_W, lin_b,
                                    Wcp, Qw, bc);
    k_pack_xt<<<16, 256, 0, stream>>>(Qw, Wcp);
    k_pack_b<<<8, 256, 0, stream>>>(W_in, 128, 128, Winp);
    k_pack_b<<<8, 256, 0, stream>>>(mlp_W1, 128, 128, W1p);
    k_pack_b<<<2, 256, 0, stream>>>(mlp_W2, 128, 32, W2p);
    k_pack_wbd<<<32, 256, 0, stream>>>(pre_W, WbBD);

    // h = relu(x @ W_in + b_in)  (MFMA, f16 out)
    k_in_mfma<<<gWave, 256, 0, stream>>>(x, Winp, b_in, hbuf);

    // layer 0
    k_preB_mfma<1><<<gWave, 256, 0, stream>>>(
        hbuf, nullptr, nullptr, nullptr, nullptr, nullptr, nullptr,
        WbBD, Bpl);
    k_agg_gemm<<<RT_CNT, 256, 0, stream>>>(
        hbuf, Bpl, fwd_nbr, rev_nbr, Wcp, bc, ybuf, bns, bns + 128);
    // layer 1 (inline BN-final of layer 0)
    k_preB_mfma<2><<<gWave, 256, 0, stream>>>(
        nullptr, ybuf, bns, bns + 128, bn_g, bn_b, hbuf,
        WbBD + (size_t)2 * 128 * 128, Bpl);
    k_agg_gemm<<<RT_CNT, 256, 0, stream>>>(
        hbuf, Bpl, fwd_nbr, rev_nbr, Wcp + (size_t)KSTEPS * 32 * 128,
        bc + 128, ybuf, bns + 256, bns + 384);

    // out = relu(bn_relu(y) @ mlp_W1 + b1) @ mlp_W2 + b2  (inline BN-final l1)
    k_mlp_mfma<<<gWave, 256, 0, stream>>>(ybuf, bns + 256, bns + 384,
                                          bn_g + 128, bn_b + 128,
                                          W1p, mlp_b1, W2p, mlp_b2, out);
}